// Round 1
// baseline (1178.821 us; speedup 1.0000x reference)
//
#include <hip/hip_runtime.h>
#include <stdint.h>

#define S_LEN 2048
#define HS_DIM 1024
#define NHEAD 16
#define HD_DIM 64
#define NBATCH 2

typedef __attribute__((ext_vector_type(8))) short short8;
typedef __attribute__((ext_vector_type(4))) float floatx4;

__device__ __forceinline__ unsigned short f2bf(float f) {
  unsigned int u = __float_as_uint(f);
  u += 0x7fffu + ((u >> 16) & 1u);   // RTN
  return (unsigned short)(u >> 16);
}

__device__ __forceinline__ floatx4 mfma_bf16(short8 a, short8 b, floatx4 c) {
  return __builtin_amdgcn_mfma_f32_16x16x32_bf16(a, b, c, 0, 0, 0);
}

__device__ __forceinline__ float bfly_max16(float v) {
  v = fmaxf(v, __shfl_xor(v, 1, 64));
  v = fmaxf(v, __shfl_xor(v, 2, 64));
  v = fmaxf(v, __shfl_xor(v, 4, 64));
  v = fmaxf(v, __shfl_xor(v, 8, 64));
  return v;
}
__device__ __forceinline__ float bfly_sum16(float v) {
  v += __shfl_xor(v, 1, 64);
  v += __shfl_xor(v, 2, 64);
  v += __shfl_xor(v, 4, 64);
  v += __shfl_xor(v, 8, 64);
  return v;
}

// ---------------------------------------------------------------- mask pack
// 1 bit per mask element; wave ballot -> one u64 per 64 ints.
__global__ __launch_bounds__(256) void pack_mask_k(const int* __restrict__ mask,
                                                   unsigned long long* __restrict__ mp) {
  int idx = blockIdx.x * 256 + threadIdx.x;
  int v = mask[idx];
  unsigned long long bal = __ballot(v != 0);
  if ((threadIdx.x & 63) == 0) mp[idx >> 6] = bal;
}

// ---------------------------------------------------------------- query column sums
// grid 32 = (B=2) x (16 row-chunks of 128); qsum[b][c] accumulated by atomics.
__global__ __launch_bounds__(256) void qsum_k(const float* __restrict__ q,
                                              float* __restrict__ qsum) {
  int b = blockIdx.x >> 4, rc = blockIdx.x & 15;
  int tid = threadIdx.x;
  float a0 = 0.f, a1 = 0.f, a2 = 0.f, a3 = 0.f;
  const float* base = q + ((size_t)b * S_LEN + rc * 128) * HS_DIM;
  for (int r = 0; r < 128; r++) {
    const float* row = base + (size_t)r * HS_DIM;
    a0 += row[tid];       a1 += row[tid + 256];
    a2 += row[tid + 512]; a3 += row[tid + 768];
  }
  atomicAdd(&qsum[b * HS_DIM + tid], a0);
  atomicAdd(&qsum[b * HS_DIM + tid + 256], a1);
  atomicAdd(&qsum[b * HS_DIM + tid + 512], a2);
  atomicAdd(&qsum[b * HS_DIM + tid + 768], a3);
}

// ---------------------------------------------------------------- h = relu(mean(q) @ Wp1 + bp1)
// grid 16 = (b, 64-col chunk). 4 i-segments of 256 reduced in LDS.
__global__ __launch_bounds__(256) void mlp_h_k(const float* __restrict__ qsum,
                                               const float* __restrict__ Wp1,
                                               const float* __restrict__ bp1,
                                               float* __restrict__ hbuf) {
  __shared__ float red[4][64];
  int b = blockIdx.x >> 3;
  int j0 = (blockIdx.x & 7) * 64;
  int tid = threadIdx.x;
  int j = j0 + (tid & 63), seg = tid >> 6;
  float partial = 0.f;
  for (int i = seg * 256; i < seg * 256 + 256; i++)
    partial += qsum[b * HS_DIM + i] * Wp1[(size_t)i * 512 + j];
  red[seg][tid & 63] = partial;
  __syncthreads();
  if (seg == 0) {
    float s = red[0][tid] + red[1][tid] + red[2][tid] + red[3][tid];
    s = s * (1.0f / 2048.0f) + bp1[j];
    hbuf[b * 512 + j] = fmaxf(s, 0.f);
  }
}

// ---------------------------------------------------------------- pattern softmax + per-(b,h) scale
__global__ __launch_bounds__(256) void patsel_k(const float* __restrict__ hbuf,
                                                const float* __restrict__ Wp2,
                                                const float* __restrict__ bp2,
                                                const float* __restrict__ patterns,
                                                float* __restrict__ patout) {
  __shared__ float logits[16];
  __shared__ float pw[2][8];
  int tid = threadIdx.x;
  int g = tid >> 4, t = tid & 15;
  int b = g >> 3, p = g & 7;
  float partial = 0.f;
  for (int i = t; i < 512; i += 16) partial += hbuf[b * 512 + i] * Wp2[i * 8 + p];
  partial += __shfl_xor(partial, 1, 64);
  partial += __shfl_xor(partial, 2, 64);
  partial += __shfl_xor(partial, 4, 64);
  partial += __shfl_xor(partial, 8, 64);
  if (t == 0) logits[g] = partial + bp2[p];
  __syncthreads();
  if (tid < 2) {
    float mx = -INFINITY;
    for (int i = 0; i < 8; i++) mx = fmaxf(mx, logits[tid * 8 + i]);
    float s = 0.f;
    for (int i = 0; i < 8; i++) { float e = __expf(logits[tid * 8 + i] - mx); pw[tid][i] = e; s += e; }
    float inv = 1.f / s;
    for (int i = 0; i < 8; i++) pw[tid][i] *= inv;
  }
  __syncthreads();
  if (tid < 32) {
    int b2 = tid >> 4, hh = tid & 15;
    float acc = 0.f;
    for (int i = 0; i < 8; i++) acc += pw[b2][i] * patterns[i * 16 + hh];
    patout[b2 * 16 + hh] = acc;
  }
}

// ---------------------------------------------------------------- GEMM: out = A[4096,1024] @ W[1024,1024] + bias
// OUT_MODE 0: store bf16 into [b][h][s][d] (QKV). OUT_MODE 1: store f32 into [m][n] (final output).
template <int OUT_MODE>
__global__ __launch_bounds__(256) void gemm_proj(const float* __restrict__ A,
                                                 const float* __restrict__ W,
                                                 const float* __restrict__ bias,
                                                 void* __restrict__ dst) {
  __shared__ __align__(16) unsigned short Al[128][40];  // [m][k] bf16
  __shared__ __align__(16) unsigned short Bl[128][40];  // [n][k] bf16 (transposed W)
  int tid = threadIdx.x;
  int w = tid >> 6, lane = tid & 63, quad = lane >> 4, l16 = lane & 15;
  int wm = w >> 1, wn = w & 1;
  int m0 = blockIdx.x * 128, n0 = blockIdx.y * 128;
  floatx4 cd[4][4];
#pragma unroll
  for (int i = 0; i < 4; i++)
#pragma unroll
    for (int jv = 0; jv < 4; jv++) cd[i][jv] = (floatx4){0.f, 0.f, 0.f, 0.f};

  for (int kt = 0; kt < HS_DIM; kt += 32) {
    __syncthreads();
    // stage A tile 128x32 (f32 -> bf16)
#pragma unroll
    for (int p = 0; p < 4; p++) {
      int idx = p * 256 + tid;
      int r = idx >> 3, c4 = (idx & 7) * 4;
      float4 v = *(const float4*)(A + (size_t)(m0 + r) * HS_DIM + kt + c4);
      uint2 pk;
      pk.x = (unsigned)f2bf(v.x) | ((unsigned)f2bf(v.y) << 16);
      pk.y = (unsigned)f2bf(v.z) | ((unsigned)f2bf(v.w) << 16);
      *(uint2*)&Al[r][c4] = pk;
    }
    // stage W tile 32x128 transposed -> Bl[n][k]
#pragma unroll
    for (int p = 0; p < 4; p++) {
      int idx = p * 256 + tid;
      int k = idx >> 5, c4 = (idx & 31) * 4;
      float4 v = *(const float4*)(W + (size_t)(kt + k) * HS_DIM + n0 + c4);
      Bl[c4 + 0][k] = f2bf(v.x);
      Bl[c4 + 1][k] = f2bf(v.y);
      Bl[c4 + 2][k] = f2bf(v.z);
      Bl[c4 + 3][k] = f2bf(v.w);
    }
    __syncthreads();
    short8 af[4], bf[4];
#pragma unroll
    for (int mi = 0; mi < 4; mi++)
      af[mi] = *(const short8*)&Al[wm * 64 + mi * 16 + l16][quad * 8];
#pragma unroll
    for (int ni = 0; ni < 4; ni++)
      bf[ni] = *(const short8*)&Bl[wn * 64 + ni * 16 + l16][quad * 8];
#pragma unroll
    for (int mi = 0; mi < 4; mi++)
#pragma unroll
      for (int ni = 0; ni < 4; ni++) cd[mi][ni] = mfma_bf16(af[mi], bf[ni], cd[mi][ni]);
  }

#pragma unroll
  for (int ni = 0; ni < 4; ni++) {
    int n = n0 + wn * 64 + ni * 16 + l16;
    float bv = bias[n];
#pragma unroll
    for (int mi = 0; mi < 4; mi++)
#pragma unroll
      for (int jj = 0; jj < 4; jj++) {
        int m = m0 + wm * 64 + mi * 16 + quad * 4 + jj;
        float val = cd[mi][ni][jj] + bv;
        if (OUT_MODE == 0) {
          int b = m >> 11, s = m & 2047, h = n >> 6, d = n & 63;
          ((unsigned short*)dst)[(((size_t)(b * NHEAD + h)) * S_LEN + s) * HD_DIM + d] = f2bf(val);
        } else {
          ((float*)dst)[(size_t)m * HS_DIM + n] = val;
        }
      }
  }
}

// ---------------------------------------------------------------- fused attention
// grid (S/64, B*NH). Two-phase (stats then recompute+normalize) flash-style, but
// attn weights are materialized to d_out (required output). ctx written f32 [b][s][h*64+d].
__global__ __launch_bounds__(256) void attn_fused(const unsigned short* __restrict__ Q,
                                                  const unsigned short* __restrict__ K,
                                                  const unsigned short* __restrict__ V,
                                                  const unsigned long long* __restrict__ mpack,
                                                  const float* __restrict__ pat,
                                                  float* __restrict__ attn_out,
                                                  float* __restrict__ ctx) {
  __shared__ __align__(16) unsigned short Ql[64][72];
  __shared__ __align__(16) unsigned short Kl[128][72];
  __shared__ __align__(16) unsigned short Vt[64][136];  // [d][kpos]
  __shared__ __align__(16) float wl[4][16][132];        // per-wave weight tile [row][col]

  const int tid = threadIdx.x;
  const int w = tid >> 6, lane = tid & 63, quad = lane >> 4, l16 = lane & 15;
  const int bh = blockIdx.y;
  const int b = bh >> 4, h = bh & 15;
  const int q0 = blockIdx.x * 64;

  const unsigned short* Qb = Q + ((size_t)bh * S_LEN + q0) * HD_DIM;
  const unsigned short* Kb = K + (size_t)bh * S_LEN * HD_DIM;
  const unsigned short* Vb = V + (size_t)bh * S_LEN * HD_DIM;
  const float scl = 0.125f * pat[bh];

  // stage Q tile (once)
#pragma unroll
  for (int p = 0; p < 2; p++) {
    int idx = p * 256 + tid;
    int r = idx >> 3, c8 = (idx & 7) * 8;
    *(uint4*)&Ql[r][c8] = *(const uint4*)(Qb + r * HD_DIM + c8);
  }
  __syncthreads();
  short8 aq[2];
  aq[0] = *(const short8*)&Ql[w * 16 + l16][quad * 8];
  aq[1] = *(const short8*)&Ql[w * 16 + l16][32 + quad * 8];

  float m_i[4], l_i[4];
#pragma unroll
  for (int jj = 0; jj < 4; jj++) { m_i[jj] = -INFINITY; l_i[jj] = 0.f; }
  const int qrow_base = q0 + w * 16 + quad * 4;

  // ---------------- phase 1: per-row max & sum(exp) ----------------
  for (int j = 0; j < 16; j++) {
    __syncthreads();
#pragma unroll
    for (int p = 0; p < 4; p++) {
      int idx = p * 256 + tid;
      int r = idx >> 3, c8 = (idx & 7) * 8;
      *(uint4*)&Kl[r][c8] = *(const uint4*)(Kb + ((size_t)(j * 128 + r)) * HD_DIM + c8);
    }
    __syncthreads();
    floatx4 c[8];
#pragma unroll
    for (int nt = 0; nt < 8; nt++) {
      floatx4 acc = (floatx4){0.f, 0.f, 0.f, 0.f};
      acc = mfma_bf16(aq[0], *(const short8*)&Kl[nt * 16 + l16][quad * 8], acc);
      acc = mfma_bf16(aq[1], *(const short8*)&Kl[nt * 16 + l16][32 + quad * 8], acc);
      c[nt] = acc;
    }
#pragma unroll
    for (int jj = 0; jj < 4; jj++) {
      size_t mb = ((size_t)b * S_LEN + qrow_base + jj) * 32 + j * 2;
      unsigned long long pk0 = mpack[mb], pk1 = mpack[mb + 1];
      float sv[8];
      float tmax = -INFINITY;
#pragma unroll
      for (int nt = 0; nt < 8; nt++) {
        int col = nt * 16 + l16;
        unsigned long long bits = (col < 64) ? pk0 : pk1;
        float s = ((bits >> (col & 63)) & 1ull) ? c[nt][jj] * scl : -1e9f;
        sv[nt] = s;
        tmax = fmaxf(tmax, s);
      }
      tmax = bfly_max16(tmax);
      float newm = fmaxf(m_i[jj], tmax);
      float ps = 0.f;
#pragma unroll
      for (int nt = 0; nt < 8; nt++) ps += __expf(sv[nt] - newm);
      ps = bfly_sum16(ps);
      l_i[jj] = l_i[jj] * __expf(m_i[jj] - newm) + ps;
      m_i[jj] = newm;
    }
  }
  float inv_l[4];
#pragma unroll
  for (int jj = 0; jj < 4; jj++) inv_l[jj] = 1.f / l_i[jj];

  // ---------------- phase 2: weights out + PV ----------------
  floatx4 o[4];
#pragma unroll
  for (int dt = 0; dt < 4; dt++) o[dt] = (floatx4){0.f, 0.f, 0.f, 0.f};
  float* arow = attn_out + (size_t)bh * S_LEN * S_LEN + (size_t)(q0 + w * 16) * S_LEN;

  for (int j = 0; j < 16; j++) {
    __syncthreads();
#pragma unroll
    for (int p = 0; p < 4; p++) {
      int idx = p * 256 + tid;
      int r = idx >> 3, c8 = (idx & 7) * 8;
      *(uint4*)&Kl[r][c8] = *(const uint4*)(Kb + ((size_t)(j * 128 + r)) * HD_DIM + c8);
      union { uint4 v; unsigned short u[8]; } U;
      U.v = *(const uint4*)(Vb + ((size_t)(j * 128 + r)) * HD_DIM + c8);
#pragma unroll
      for (int i = 0; i < 8; i++) Vt[c8 + i][r] = U.u[i];
    }
    __syncthreads();
    floatx4 c[8];
#pragma unroll
    for (int nt = 0; nt < 8; nt++) {
      floatx4 acc = (floatx4){0.f, 0.f, 0.f, 0.f};
      acc = mfma_bf16(aq[0], *(const short8*)&Kl[nt * 16 + l16][quad * 8], acc);
      acc = mfma_bf16(aq[1], *(const short8*)&Kl[nt * 16 + l16][32 + quad * 8], acc);
      c[nt] = acc;
    }
#pragma unroll
    for (int jj = 0; jj < 4; jj++) {
      size_t mb = ((size_t)b * S_LEN + qrow_base + jj) * 32 + j * 2;
      unsigned long long pk0 = mpack[mb], pk1 = mpack[mb + 1];
#pragma unroll
      for (int nt = 0; nt < 8; nt++) {
        int col = nt * 16 + l16;
        unsigned long long bits = (col < 64) ? pk0 : pk1;
        float s = ((bits >> (col & 63)) & 1ull) ? c[nt][jj] * scl : -1e9f;
        float wv = __expf(s - m_i[jj]) * inv_l[jj];
        wl[w][quad * 4 + jj][col] = wv;  // wave-private LDS; DS in-order per wave
      }
    }
    // coalesced store of this wave's 16x128 weight tile
#pragma unroll
    for (int p = 0; p < 8; p++) {
      int r = p * 2 + (lane >> 5), c4 = (lane & 31) * 4;
      *(float4*)(arow + (size_t)r * S_LEN + j * 128 + c4) = *(const float4*)&wl[w][r][c4];
    }
    // PV: A-frags from wl (f32 -> bf16), B-frags from Vt
#pragma unroll
    for (int ks = 0; ks < 4; ks++) {
      float4 wa0 = *(const float4*)&wl[w][l16][ks * 32 + quad * 8];
      float4 wa1 = *(const float4*)&wl[w][l16][ks * 32 + quad * 8 + 4];
      short8 af;
      af[0] = (short)f2bf(wa0.x); af[1] = (short)f2bf(wa0.y);
      af[2] = (short)f2bf(wa0.z); af[3] = (short)f2bf(wa0.w);
      af[4] = (short)f2bf(wa1.x); af[5] = (short)f2bf(wa1.y);
      af[6] = (short)f2bf(wa1.z); af[7] = (short)f2bf(wa1.w);
#pragma unroll
      for (int dt = 0; dt < 4; dt++)
        o[dt] = mfma_bf16(af, *(const short8*)&Vt[dt * 16 + l16][ks * 32 + quad * 8], o[dt]);
    }
  }

  // write context f32 into [b][s][h*64+d]
#pragma unroll
  for (int dt = 0; dt < 4; dt++)
#pragma unroll
    for (int jj = 0; jj < 4; jj++) {
      int q = qrow_base + jj;
      ctx[((size_t)b * S_LEN + q) * HS_DIM + h * HD_DIM + dt * 16 + l16] = o[dt][jj];
    }
}

// ---------------------------------------------------------------- launch
extern "C" void kernel_launch(void* const* d_in, const int* in_sizes, int n_in,
                              void* d_out, int out_size, void* d_ws, size_t ws_size,
                              hipStream_t stream) {
  const float* query = (const float*)d_in[0];
  const float* key   = (const float*)d_in[1];
  const float* value = (const float*)d_in[2];
  const int*   amask = (const int*)d_in[3];
  const float* Wq = (const float*)d_in[4];
  const float* bq = (const float*)d_in[5];
  const float* Wk = (const float*)d_in[6];
  const float* bk = (const float*)d_in[7];
  const float* Wv = (const float*)d_in[8];
  const float* bv = (const float*)d_in[9];
  const float* Wo = (const float*)d_in[10];
  const float* bo = (const float*)d_in[11];
  const float* Wp1 = (const float*)d_in[12];
  const float* bp1 = (const float*)d_in[13];
  const float* Wp2 = (const float*)d_in[14];
  const float* bp2 = (const float*)d_in[15];
  const float* patterns = (const float*)d_in[16];

  float* out = (float*)d_out;                       // [2,2048,1024] f32
  float* attn = out + (size_t)NBATCH * S_LEN * HS_DIM;  // [2,16,2048,2048] f32

  char* ws = (char*)d_ws;
  float* qsum = (float*)(ws + 0);                              // 8 KiB
  float* hbuf = (float*)(ws + 8192);                           // 4 KiB
  float* patb = (float*)(ws + 12288);                          // 128 B
  unsigned long long* mpack = (unsigned long long*)(ws + 16384);  // 1 MiB
  unsigned short* Qw  = (unsigned short*)(ws + (size_t)2097152);      // 8 MiB
  unsigned short* Kw  = (unsigned short*)(ws + (size_t)10485760);     // 8 MiB
  unsigned short* Vw  = (unsigned short*)(ws + (size_t)18874368);     // 8 MiB
  float*          ctx = (float*)(ws + (size_t)27262976);             // 16 MiB

  hipMemsetAsync(qsum, 0, 8192, stream);

  pack_mask_k<<<dim3(32768), dim3(256), 0, stream>>>(amask, mpack);
  qsum_k<<<dim3(32), dim3(256), 0, stream>>>(query, qsum);
  mlp_h_k<<<dim3(16), dim3(256), 0, stream>>>(qsum, Wp1, bp1, hbuf);
  patsel_k<<<dim3(1), dim3(256), 0, stream>>>(hbuf, Wp2, bp2, patterns, patb);

  gemm_proj<0><<<dim3(32, 8), dim3(256), 0, stream>>>(query, Wq, bq, (void*)Qw);
  gemm_proj<0><<<dim3(32, 8), dim3(256), 0, stream>>>(key,   Wk, bk, (void*)Kw);
  gemm_proj<0><<<dim3(32, 8), dim3(256), 0, stream>>>(value, Wv, bv, (void*)Vw);

  attn_fused<<<dim3(32, 32), dim3(256), 0, stream>>>(Qw, Kw, Vw, mpack, patb, attn, ctx);

  gemm_proj<1><<<dim3(32, 8), dim3(256), 0, stream>>>(ctx, Wo, bo, (void*)out);
}